// Round 5
// baseline (130.322 us; speedup 1.0000x reference)
//
#include <hip/hip_runtime.h>

// RelativeAttentionPositions: out[b,h,s,t] = dot(tensor[b,h,s,:], E[clip(t-s,-128,128)+128,:]) + bias[h]
// B=4 H=16 S=1024 D=64 MAX_REL=128 VOCAB=257.
// v5: two kernels.
//  k1: MFMA computes margin-replicated c-tables (bias baked in) -> 36 MB workspace.
//  k2: dense-front expand: grid-stride so at any instant all 2048 blocks write ONE
//      contiguous ~8MB window (fill-kernel-shaped write stream), one aligned 8B
//      gather + float4 store per lane, branchless. Tests/fixes the hypothesis that
//      1024 private per-block write streams were costing 2x DRAM write efficiency.
//
// c-row layout (u16 bf16, pitch CPITCH=276 = 552 B): R[0..pad+3]=c0 margin,
// R[pad+4+v]=c[v] (v=0..256), R[pad+261..267]=c256 margin, pad=s&3.
// m0 = t0 + (s&3) + 132 - s is always ==0 mod 4 -> ds/global b64 reads stay aligned;
// clamp(m0,0,264) lands in the replicated margins for the saturated bands.

constexpr int S_     = 1024;
constexpr int D_     = 64;
constexpr int BQ     = 64;    // rows per compute block = 4 waves x 16
constexpr int CPITCH = 276;   // u16 pitch (552 B, 8B-aligned rows)

typedef __attribute__((ext_vector_type(8))) short short8;   // 8 bf16 (MFMA A/B frag)
typedef __attribute__((ext_vector_type(4))) float f32x4;    // MFMA C/D frag

__device__ __forceinline__ unsigned short f2bf(float x) {
  unsigned u = __float_as_uint(x);
  return (unsigned short)((u + 0x7fffu + ((u >> 16) & 1u)) >> 16);  // RNE
}
__device__ __forceinline__ short8 pack8(float4 a, float4 b) {
  short8 r;
  r[0] = (short)f2bf(a.x); r[1] = (short)f2bf(a.y);
  r[2] = (short)f2bf(a.z); r[3] = (short)f2bf(a.w);
  r[4] = (short)f2bf(b.x); r[5] = (short)f2bf(b.y);
  r[6] = (short)f2bf(b.z); r[7] = (short)f2bf(b.w);
  return r;
}

// ---- kernel 1: c[g][*] tables -> workspace (g = bh*1024 + s, 64 rows/block) ----
__global__ __launch_bounds__(256, 4)
void relpos_c(const float* __restrict__ tensor,
              const float* __restrict__ relk,
              const float* __restrict__ bias,
              unsigned short* __restrict__ c_ws) {
  __shared__ __align__(16) unsigned short c_lds[BQ * CPITCH];  // 35328 B

  const int tid  = threadIdx.x;
  const int lane = tid & 63;
  const int w    = tid >> 6;
  const int bh   = blockIdx.x >> 4;
  const int s0   = (blockIdx.x & 15) * BQ;
  const int h    = bh & 15;
  const int l15  = lane & 15;
  const int l4   = lane >> 4;
  const int r0   = 16 * w + l4 * 4;

  const float* xrow = tensor + ((size_t)(bh * S_ + s0 + 16 * w + l15)) * D_ + l4 * 8;
  short8 a0 = pack8(*reinterpret_cast<const float4*>(xrow),
                    *reinterpret_cast<const float4*>(xrow + 4));
  short8 a1 = pack8(*reinterpret_cast<const float4*>(xrow + 32),
                    *reinterpret_cast<const float4*>(xrow + 36));
  const float bv = bias[h];

#pragma unroll 2
  for (int nt = 0; nt < 17; ++nt) {
    const int vcol = 16 * nt + l15;
    const int erow = vcol > 256 ? 256 : vcol;
    const float* ep = relk + (size_t)erow * D_ + l4 * 8;
    short8 b0 = pack8(*reinterpret_cast<const float4*>(ep),
                      *reinterpret_cast<const float4*>(ep + 4));
    short8 b1 = pack8(*reinterpret_cast<const float4*>(ep + 32),
                      *reinterpret_cast<const float4*>(ep + 36));
    f32x4 acc = {0.f, 0.f, 0.f, 0.f};
    acc = __builtin_amdgcn_mfma_f32_16x16x32_bf16(a0, b0, acc, 0, 0, 0);
    acc = __builtin_amdgcn_mfma_f32_16x16x32_bf16(a1, b1, acc, 0, 0, 0);
    // D mapping [m89]: col = l15 (= v-16nt), row = l4*4 + i
    if (vcol <= 256) {
#pragma unroll
      for (int i = 0; i < 4; ++i)
        c_lds[(r0 + i) * CPITCH + i + 4 + vcol] = f2bf(acc[i] + bv);  // pad = (s&3) = i
    }
    if (l15 == 0 && nt == 0) {        // holds c[row][0] -> left margin
#pragma unroll
      for (int i = 0; i < 4; ++i) {
        const unsigned short cv = f2bf(acc[i] + bv);
        for (int j = 0; j <= i + 3; ++j) c_lds[(r0 + i) * CPITCH + j] = cv;
      }
    }
    if (l15 == 0 && nt == 16) {       // holds c[row][256] -> right margin
#pragma unroll
      for (int i = 0; i < 4; ++i) {
        const unsigned short cv = f2bf(acc[i] + bv);
        for (int j = i + 261; j < 268; ++j) c_lds[(r0 + i) * CPITCH + j] = cv;
      }
    }
  }
  __syncthreads();

  // coalesced LDS -> workspace copy (block's rows are contiguous: g = bid*64 + rl)
  const uint4* src = reinterpret_cast<const uint4*>(c_lds);
  uint4* dst = reinterpret_cast<uint4*>(c_ws + (size_t)blockIdx.x * (BQ * CPITCH));
  constexpr int NV4 = BQ * CPITCH / 8;   // 2208
#pragma unroll
  for (int i = 0; i < 9; ++i) {
    int idx = tid + 256 * i;
    if (idx < NV4) dst[idx] = src[idx];
  }
}

// ---- kernel 2: dense-front expand ----
__global__ __launch_bounds__(256, 8)
void relpos_expand(const unsigned short* __restrict__ c_ws,
                   float* __restrict__ out) {
  const int tid = threadIdx.x;
  const int bid = blockIdx.x;
  const int t0  = tid << 2;
#pragma unroll 4
  for (int it = 0; it < 32; ++it) {
    const int g = (it << 11) + bid;   // global row; front = contiguous 2048 rows
    const int s = g & (S_ - 1);
    int m0 = t0 + (s & 3) + 132 - s;
    m0 = m0 < 0 ? 0 : (m0 > 264 ? 264 : m0);          // always ==0 mod 4
    const uint2 q = *reinterpret_cast<const uint2*>(&c_ws[(size_t)g * CPITCH + m0]);
    float4 o;
    o.x = __uint_as_float(q.x << 16);
    o.y = __uint_as_float(q.x & 0xffff0000u);
    o.z = __uint_as_float(q.y << 16);
    o.w = __uint_as_float(q.y & 0xffff0000u);
    *reinterpret_cast<float4*>(&out[((size_t)g << 10) + t0]) = o;
  }
}

extern "C" void kernel_launch(void* const* d_in, const int* in_sizes, int n_in,
                              void* d_out, int out_size, void* d_ws, size_t ws_size,
                              hipStream_t stream) {
  const float* tensor = (const float*)d_in[0];
  const float* relk   = (const float*)d_in[1];
  // d_in[2] = rel_values_emb (unused in forward), d_in[4] = max_relative_position (=128)
  const float* bias   = (const float*)d_in[3];
  float* out          = (float*)d_out;
  unsigned short* c_ws = (unsigned short*)d_ws;      // needs 36.2 MB, ws is ~1 GiB

  relpos_c<<<dim3(1024), dim3(256), 0, stream>>>(tensor, relk, bias, c_ws);
  relpos_expand<<<dim3(2048), dim3(256), 0, stream>>>(c_ws, out);
}

// Round 7
// 79.970 us; speedup vs baseline: 1.6296x; 1.6296x over previous
//
#include <hip/hip_runtime.h>

// RelativeAttentionPositions: out[b,h,s,t] = dot(tensor[b,h,s,:], E[clip(t-s,-128,128)+128,:]) + bias[h]
// B=4 H=16 S=1024 D=64 MAX_REL=128 VOCAB=257.
// v6b = v4 + NON-TEMPORAL stores on the 268MB output stream (and nt loads on the
// read-once tensor), with the nt intrinsics applied to clang ext_vector types
// (HIP float4 class is rejected by __builtin_nontemporal_store).
// Everything else identical to v4 (MFMA c-table, margin-replicated LDS rows,
// flat branchless float4 expand, 1024 blocks / 4 per CU).
//
// c-row layout (u16 bf16, pitch CPITCH=276 = 552 B): R[0..pad+3]=c0 margin,
// R[pad+4+v]=c[v] (v=0..256), R[pad+261..267]=c256 margin, pad=s&3.
// m0 = t0 + (s&3) + 132 - s is always ==0 mod 4 -> aligned b64 LDS reads;
// clamp(m0,0,264) lands in the replicated margins for the saturated bands.

constexpr int S_     = 1024;
constexpr int D_     = 64;
constexpr int BQ     = 64;    // rows per block = 4 waves x 16
constexpr int CPITCH = 276;   // u16 pitch (552 B, 8B-aligned rows)

typedef __attribute__((ext_vector_type(8))) short short8;   // 8 bf16 (MFMA A/B frag)
typedef __attribute__((ext_vector_type(4))) float f32x4;    // MFMA C/D frag + nt-store payload

__device__ __forceinline__ unsigned short f2bf(float x) {
  unsigned u = __float_as_uint(x);
  return (unsigned short)((u + 0x7fffu + ((u >> 16) & 1u)) >> 16);  // RNE
}
__device__ __forceinline__ short8 pack8(f32x4 a, f32x4 b) {
  short8 r;
  r[0] = (short)f2bf(a.x); r[1] = (short)f2bf(a.y);
  r[2] = (short)f2bf(a.z); r[3] = (short)f2bf(a.w);
  r[4] = (short)f2bf(b.x); r[5] = (short)f2bf(b.y);
  r[6] = (short)f2bf(b.z); r[7] = (short)f2bf(b.w);
  return r;
}
__device__ __forceinline__ f32x4 ntload4(const float* p) {
  return __builtin_nontemporal_load(reinterpret_cast<const f32x4*>(p));
}
__device__ __forceinline__ f32x4 ld4(const float* p) {
  return *reinterpret_cast<const f32x4*>(p);
}

__global__ __launch_bounds__(256, 4)
void relpos_v6(const float* __restrict__ tensor,
               const float* __restrict__ relk,
               const float* __restrict__ bias,
               float* __restrict__ out) {
  __shared__ __align__(16) unsigned short c_lds[BQ * CPITCH];  // 35328 B -> 4 blocks/CU

  const int tid  = threadIdx.x;
  const int lane = tid & 63;
  const int w    = tid >> 6;          // wave id; wave computes rows 16w..16w+15
  const int bh   = blockIdx.x >> 4;
  const int s0   = (blockIdx.x & 15) * BQ;
  const int h    = bh & 15;
  const int l15  = lane & 15;
  const int l4   = lane >> 4;
  const int r0   = 16 * w + l4 * 4;   // first of the 4 block-local rows this lane holds

  // ---- A fragments: rows s0+16w+l15, k = l4*8 (+0 / +32); read-once -> nt loads ----
  const float* xrow = tensor + ((size_t)(bh * S_ + s0 + 16 * w + l15)) * D_ + l4 * 8;
  short8 a0 = pack8(ntload4(xrow), ntload4(xrow + 4));
  short8 a1 = pack8(ntload4(xrow + 32), ntload4(xrow + 36));
  const float bv = bias[h];

  // ---- compute c-table with margins (E stays normally cached: reused by all blocks) ----
#pragma unroll 2
  for (int nt = 0; nt < 17; ++nt) {
    const int vcol = 16 * nt + l15;
    const int erow = vcol > 256 ? 256 : vcol;
    const float* ep = relk + (size_t)erow * D_ + l4 * 8;
    short8 b0 = pack8(ld4(ep), ld4(ep + 4));
    short8 b1 = pack8(ld4(ep + 32), ld4(ep + 36));
    f32x4 acc = {0.f, 0.f, 0.f, 0.f};
    acc = __builtin_amdgcn_mfma_f32_16x16x32_bf16(a0, b0, acc, 0, 0, 0);
    acc = __builtin_amdgcn_mfma_f32_16x16x32_bf16(a1, b1, acc, 0, 0, 0);
    // D mapping [m89]: col = l15 (= v-16nt), row = l4*4 + i
    if (vcol <= 256) {
#pragma unroll
      for (int i = 0; i < 4; ++i)
        c_lds[(r0 + i) * CPITCH + i + 4 + vcol] = f2bf(acc[i] + bv);  // pad = (s&3) = i
    }
    if (l15 == 0 && nt == 0) {        // holds c[row][0] -> left margin
#pragma unroll
      for (int i = 0; i < 4; ++i) {
        const unsigned short cv = f2bf(acc[i] + bv);
        for (int j = 0; j <= i + 3; ++j) c_lds[(r0 + i) * CPITCH + j] = cv;
      }
    }
    if (l15 == 0 && nt == 16) {       // holds c[row][256] -> right margin
#pragma unroll
      for (int i = 0; i < 4; ++i) {
        const unsigned short cv = f2bf(acc[i] + bv);
        for (int j = i + 261; j < 268; ++j) c_lds[(r0 + i) * CPITCH + j] = cv;
      }
    }
  }
  __syncthreads();

  // ---- expand: flat sweep, NON-TEMPORAL f32x4 stores ----
  float* obase = out + ((size_t)bh * S_ + s0) * (size_t)S_;
  const int mc = 132 - s0;            // m0 = t0 + (rl&3) + 132 - s0 - rl
#pragma unroll 4
  for (int it = 0; it < 64; ++it) {
    const int idx = it * 256 + tid;   // f32x4 index within block region (0..16383)
    const int rl  = idx >> 8;         // block-local row 0..63
    const int t0  = (idx & 255) << 2;
    int m0 = t0 + (rl & 3) + mc - rl;
    m0 = m0 < 0 ? 0 : (m0 > 264 ? 264 : m0);
    const uint2 q = *reinterpret_cast<const uint2*>(&c_lds[rl * CPITCH + m0]);
    f32x4 o;
    o.x = __uint_as_float(q.x << 16);
    o.y = __uint_as_float(q.x & 0xffff0000u);
    o.z = __uint_as_float(q.y << 16);
    o.w = __uint_as_float(q.y & 0xffff0000u);
    __builtin_nontemporal_store(o, reinterpret_cast<f32x4*>(&obase[(size_t)idx * 4]));
  }
}

extern "C" void kernel_launch(void* const* d_in, const int* in_sizes, int n_in,
                              void* d_out, int out_size, void* d_ws, size_t ws_size,
                              hipStream_t stream) {
  const float* tensor = (const float*)d_in[0];
  const float* relk   = (const float*)d_in[1];
  // d_in[2] = rel_values_emb (unused in forward), d_in[4] = max_relative_position (=128)
  const float* bias   = (const float*)d_in[3];
  float* out          = (float*)d_out;

  const int B = 4, H = 16;
  dim3 grid(B * H * (S_ / BQ));   // 1024 blocks, 4/CU, fully resident
  dim3 block(256);
  relpos_v6<<<grid, block, 0, stream>>>(tensor, relk, bias, out);
}

// Round 8
// 72.974 us; speedup vs baseline: 1.7859x; 1.0959x over previous
//
#include <hip/hip_runtime.h>

// RelativeAttentionPositions: out[b,h,s,t] = dot(tensor[b,h,s,:], E[clip(t-s,-128,128)+128,:]) + bias[h]
// B=4 H=16 S=1024 D=64 MAX_REL=128 VOCAB=257.
// v8: fill-shaped execution. 512 blocks (2/CU, 8 waves/CU — LOW wave count like the
// 6.9TB/s fill kernel), each block owns 512KB contiguous output = 2 chunks of 64 rows.
// Per chunk: MFMA c-table (nt-outer loop, E packed once per nt), then expand with
// ds_read_b128 (8 c-vals per 32B of output), unroll 8 -> deep independent store runs.
//
// c-row layout (u16 bf16, pitch CP=280 = 560 B, 16B-aligned rows), pad = s&7:
//   [0, pad+7] = c0 margin, [pad+8+v] = c[v] (v=0..256), [pad+265, 279] = c256 margin.
// m0 = t0 + (s&7) + 136 - s  is always ==0 mod 8 (t0 mult of 8, (s&7)-s = -8k)
// -> 16B-aligned b128 reads; clamp(m0,0,272): 0 and 272 both ==0 mod 8, and the
// variable-pad margins absorb straddling chunks exactly (reads [m0,m0+7] stay in-row).

constexpr int S_ = 1024;
constexpr int D_ = 64;
constexpr int CP = 280;      // u16 pitch (560 B)
constexpr int ROWS = 64;     // rows per chunk
constexpr int CHUNKS = 2;    // chunks per block

typedef __attribute__((ext_vector_type(8))) short short8;   // 8 bf16 (MFMA A/B frag)
typedef __attribute__((ext_vector_type(4))) float f32x4;    // MFMA C/D frag

__device__ __forceinline__ unsigned short f2bf(float x) {
  unsigned u = __float_as_uint(x);
  return (unsigned short)((u + 0x7fffu + ((u >> 16) & 1u)) >> 16);  // RNE
}
__device__ __forceinline__ f32x4 ld4(const float* p) {
  return *reinterpret_cast<const f32x4*>(p);
}
__device__ __forceinline__ short8 pack8(f32x4 a, f32x4 b) {
  short8 r;
  r[0] = (short)f2bf(a.x); r[1] = (short)f2bf(a.y);
  r[2] = (short)f2bf(a.z); r[3] = (short)f2bf(a.w);
  r[4] = (short)f2bf(b.x); r[5] = (short)f2bf(b.y);
  r[6] = (short)f2bf(b.z); r[7] = (short)f2bf(b.w);
  return r;
}

__global__ __launch_bounds__(256, 1)
void relpos_v8(const float* __restrict__ tensor,
               const float* __restrict__ relk,
               const float* __restrict__ bias,
               float* __restrict__ out) {
  __shared__ __align__(16) unsigned short c_lds[ROWS * CP];  // 35840 B

  const int tid  = threadIdx.x;
  const int lane = tid & 63;
  const int w    = tid >> 6;
  const int l15  = lane & 15;
  const int l4   = lane >> 4;
  const int r0   = 16 * w + l4 * 4;     // block-local first row of this lane's D frags
  const int pb   = 4 * (l4 & 1);        // = r0 & 7 (base pad for rows r0..r0+3)

  for (int ch = 0; ch < CHUNKS; ++ch) {
    const int cid = blockIdx.x * CHUNKS + ch;   // 0..1023
    const int bh  = cid >> 4;
    const int s0  = (cid & 15) * ROWS;
    const float bv = bias[bh & 15];

    // ---- A fragments: rows s0 + 16w + l15, k = l4*8 (+0 / +32) ----
    const float* xrow = tensor + ((size_t)(bh * S_ + s0 + 16 * w + l15)) * D_ + l4 * 8;
    short8 a0 = pack8(ld4(xrow),      ld4(xrow + 4));
    short8 a1 = pack8(ld4(xrow + 32), ld4(xrow + 36));

    if (ch) __syncthreads();   // previous chunk's expand reads must finish first

    // ---- compute c-table (margins + window), bias baked in ----
#pragma unroll 2
    for (int nt = 0; nt < 17; ++nt) {
      const int vcol = 16 * nt + l15;
      const int erow = vcol > 256 ? 256 : vcol;
      const float* ep = relk + (size_t)erow * D_ + l4 * 8;
      short8 b0 = pack8(ld4(ep),      ld4(ep + 4));
      short8 b1 = pack8(ld4(ep + 32), ld4(ep + 36));
      f32x4 acc = {0.f, 0.f, 0.f, 0.f};
      acc = __builtin_amdgcn_mfma_f32_16x16x32_bf16(a0, b0, acc, 0, 0, 0);
      acc = __builtin_amdgcn_mfma_f32_16x16x32_bf16(a1, b1, acc, 0, 0, 0);
      // D mapping [m89]: col = l15 (= v-16nt), row = r0 + i
      if (vcol <= 256) {
#pragma unroll
        for (int i = 0; i < 4; ++i)
          c_lds[(r0 + i) * CP + pb + i + 8 + vcol] = f2bf(acc[i] + bv);  // pad = pb+i
      }
      if (l15 == 0 && nt == 0) {          // lane holds c[row][0] -> left margin [0, pad+7]
#pragma unroll
        for (int i = 0; i < 4; ++i) {
          const unsigned short cv = f2bf(acc[i] + bv);
          const int pad = pb + i;
          for (int j = 0; j <= pad + 7; ++j) c_lds[(r0 + i) * CP + j] = cv;
        }
      }
      if (l15 == 0 && nt == 16) {         // lane holds c[row][256] -> right margin [pad+265, 279]
#pragma unroll
        for (int i = 0; i < 4; ++i) {
          const unsigned short cv = f2bf(acc[i] + bv);
          const int pad = pb + i;
          for (int j = pad + 265; j < CP; ++j) c_lds[(r0 + i) * CP + j] = cv;
        }
      }
    }
    __syncthreads();

    // ---- expand: 256 KB contiguous, b128 gather -> 2 f32x4 stores per 32 B ----
    float* obase = out + ((size_t)(bh * S_ + s0)) * (size_t)S_;
    const int mc = 136 - s0;
#pragma unroll 8
    for (int it = 0; it < 32; ++it) {
      const int idx = it * 256 + tid;     // 0..8191 (32-B chunks of the 256 KB region)
      const int rl  = idx >> 7;           // block-local row 0..63
      const int t0  = (idx & 127) << 3;   // 0..1016, step 8
      int m0 = t0 + (rl & 7) + mc - rl;
      m0 = m0 < 0 ? 0 : (m0 > 272 ? 272 : m0);   // stays ==0 mod 8
      const uint4 q = *reinterpret_cast<const uint4*>(&c_lds[rl * CP + m0]);
      f32x4 o0, o1;
      o0.x = __uint_as_float(q.x << 16);
      o0.y = __uint_as_float(q.x & 0xffff0000u);
      o0.z = __uint_as_float(q.y << 16);
      o0.w = __uint_as_float(q.y & 0xffff0000u);
      o1.x = __uint_as_float(q.z << 16);
      o1.y = __uint_as_float(q.z & 0xffff0000u);
      o1.z = __uint_as_float(q.w << 16);
      o1.w = __uint_as_float(q.w & 0xffff0000u);
      float* p = obase + ((size_t)rl << 10) + t0;
      *reinterpret_cast<f32x4*>(p)     = o0;
      *reinterpret_cast<f32x4*>(p + 4) = o1;
    }
  }
}

extern "C" void kernel_launch(void* const* d_in, const int* in_sizes, int n_in,
                              void* d_out, int out_size, void* d_ws, size_t ws_size,
                              hipStream_t stream) {
  const float* tensor = (const float*)d_in[0];
  const float* relk   = (const float*)d_in[1];
  // d_in[2] = rel_values_emb (unused in forward), d_in[4] = max_relative_position (=128)
  const float* bias   = (const float*)d_in[3];
  float* out          = (float*)d_out;

  dim3 grid(512);    // 2 blocks/CU, 8 waves/CU (fill-like low occupancy, deep streams)
  dim3 block(256);
  relpos_v8<<<grid, block, 0, stream>>>(tensor, relk, bias, out);
}